// Round 1
// baseline (125.824 us; speedup 1.0000x reference)
//
#include <hip/hip_runtime.h>
#include <hip/hip_bf16.h>

// Ensemble SRN: 8 sub-models (2x2x2 octants), MLP 3->128->128->128->1, ReLU.
// Strategy: bucket points by model, then per-model bf16-MFMA tile pipeline.
// ws layout: [0,64)   counts[8] + cursors[8]
//            [64, 64+4N)          perm[N]
//            [64+4N, +256KB)      Wt1 bf16 [8][128][128] (transposed: [n][k])
//            [.., +256KB)         Wt2 bf16 [8][128][128]
// total ~1.05 MB of ws.

#define HDIM 128
#define LDSH 136      // padded LDS stride (bf16 elems): 272B rows -> 2-way bank aliasing (free)
#define TILE 64
#define NMODEL 8
#define TILES_X 288   // expected tiles/model ~256; grid-stride loop covers any skew

typedef __bf16 bf16x8 __attribute__((ext_vector_type(8)));
typedef __bf16 bf16x4 __attribute__((ext_vector_type(4)));
typedef float  f32x4  __attribute__((ext_vector_type(4)));

__device__ __forceinline__ int model_of(float x0, float x1, float x2) {
  // match reference exactly: u=(x+1)/(2+1e-6); cell=int(u_flipped*2); idx=c0+2c1+4c2
  const float den = 2.000001f;          // f32(2.0 + 1e-6)
  float u0 = (x0 + 1.0f) / den;
  float u1 = (x1 + 1.0f) / den;
  float u2 = (x2 + 1.0f) / den;
  int c0 = (int)(u2 * 2.0f);
  int c1 = (int)(u1 * 2.0f);
  int c2 = (int)(u0 * 2.0f);
  return c0 + (c1 << 1) + (c2 << 2);
}

// ---------- prep: transpose W1,W2 -> bf16 Wt[n][k]; zero counters ----------
__global__ void srn_prep(const float* __restrict__ W1, const float* __restrict__ W2,
                         __bf16* __restrict__ Wt1, __bf16* __restrict__ Wt2,
                         int* __restrict__ counts)
{
  const int t = blockIdx.x * blockDim.x + threadIdx.x;   // 0 .. M*H*H-1
  if (blockIdx.x == 0 && threadIdx.x < 2 * NMODEL) counts[threadIdx.x] = 0;
  const int m = t >> 14;
  const int n = (t >> 7) & 127;
  const int k = t & 127;
  const int src = (m << 14) + (k << 7) + n;
  Wt1[t] = (__bf16)W1[src];
  Wt2[t] = (__bf16)W2[src];
}

// ---------- count ----------
__global__ void srn_count(const float* __restrict__ x, int* __restrict__ counts, int N)
{
  __shared__ int lc[NMODEL];
  const int tid = threadIdx.x;
  if (tid < NMODEL) lc[tid] = 0;
  __syncthreads();
  const int i = blockIdx.x * blockDim.x + tid;
  if (i < N) {
    int id = model_of(x[3*i], x[3*i+1], x[3*i+2]);
    atomicAdd(&lc[id], 1);
  }
  __syncthreads();
  if (tid < NMODEL && lc[tid] > 0) atomicAdd(&counts[tid], lc[tid]);
}

// ---------- scan: cursors = exclusive prefix of counts ----------
__global__ void srn_scan(const int* __restrict__ counts, int* __restrict__ cursors)
{
  if (threadIdx.x == 0) {
    int run = 0;
    for (int m = 0; m < NMODEL; ++m) { cursors[m] = run; run += counts[m]; }
  }
}

// ---------- scatter: perm[slot] = point id, block-aggregated atomics ----------
__global__ void srn_scatter(const float* __restrict__ x, int* __restrict__ cursors,
                            int* __restrict__ perm, int N)
{
  __shared__ int lc[NMODEL], lb[NMODEL];
  const int tid = threadIdx.x;
  if (tid < NMODEL) lc[tid] = 0;
  __syncthreads();
  const int i = blockIdx.x * blockDim.x + tid;
  int id = 0, r = 0;
  bool valid = (i < N);
  if (valid) {
    id = model_of(x[3*i], x[3*i+1], x[3*i+2]);
    r = atomicAdd(&lc[id], 1);
  }
  __syncthreads();
  if (tid < NMODEL && lc[tid] > 0) lb[tid] = atomicAdd(&cursors[tid], lc[tid]);
  __syncthreads();
  if (valid) perm[lb[id] + r] = i;
}

// ---------- GEMM layer: hOut = relu(hIn @ W + b), [64x128]x[128x128] bf16 MFMA ----------
// wave w owns col-tiles {2w, 2w+1} for all 4 row-tiles -> no intra-block B duplication.
__device__ __forceinline__ void gemm_relu(const __bf16* __restrict__ hIn,
                                          __bf16* __restrict__ hOut,
                                          const __bf16* __restrict__ Wt,
                                          const float* __restrict__ bias,
                                          int wave, int l16, int quad)
{
  const int n0 = wave * 32;
  f32x4 acc[4][2] = {};
  #pragma unroll
  for (int kk = 0; kk < 4; ++kk) {
    const int kOff = kk * 32 + quad * 8;
    bf16x8 bv0 = *(const bf16x8*)(Wt + (n0 + l16) * HDIM + kOff);
    bf16x8 bv1 = *(const bf16x8*)(Wt + (n0 + 16 + l16) * HDIM + kOff);
    #pragma unroll
    for (int r = 0; r < 4; ++r) {
      bf16x8 av = *(const bf16x8*)(hIn + (r * 16 + l16) * LDSH + kOff);
      acc[r][0] = __builtin_amdgcn_mfma_f32_16x16x32_bf16(av, bv0, acc[r][0], 0, 0, 0);
      acc[r][1] = __builtin_amdgcn_mfma_f32_16x16x32_bf16(av, bv1, acc[r][1], 0, 0, 0);
    }
  }
  const float bv0 = bias[n0 + l16];
  const float bv1 = bias[n0 + 16 + l16];
  #pragma unroll
  for (int r = 0; r < 4; ++r) {
    #pragma unroll
    for (int c = 0; c < 2; ++c) {
      const int n = n0 + c * 16 + l16;
      const float bb = c ? bv1 : bv0;
      #pragma unroll
      for (int i = 0; i < 4; ++i) {
        const int row = r * 16 + quad * 4 + i;   // C/D: col=lane&15, row=quad*4+reg
        float v = acc[r][c][i] + bb;
        hOut[row * LDSH + n] = (__bf16)fmaxf(v, 0.0f);
      }
    }
  }
}

// ---------- main: per-model tiled MLP ----------
__global__ __launch_bounds__(256, 4)
void srn_main(const float* __restrict__ x,
              const float* __restrict__ W0, const float* __restrict__ b0,
              const float* __restrict__ b1, const float* __restrict__ b2,
              const float* __restrict__ W3, const float* __restrict__ b3,
              const float* __restrict__ mins, const float* __restrict__ maxs,
              const __bf16* __restrict__ Wt1, const __bf16* __restrict__ Wt2,
              const int* __restrict__ counts, const int* __restrict__ perm,
              float* __restrict__ out)
{
  __shared__ __align__(16) __bf16 hA[TILE * LDSH];
  __shared__ __align__(16) __bf16 hB[TILE * LDSH];
  __shared__ float xs[TILE][3];
  __shared__ int   pid[TILE];
  __shared__ float w0s[3 * HDIM];
  __shared__ float b0s[HDIM], b1s[HDIM], b2s[HDIM], w3s[HDIM];
  __shared__ int   s_base[2];

  const int m = blockIdx.y;
  const int tid = threadIdx.x;

  if (tid == 0) {
    int off = 0;
    for (int j = 0; j < m; ++j) off += counts[j];
    s_base[0] = off;
    s_base[1] = counts[m];
  }
  if (tid < HDIM) {
    w0s[tid]          = W0[m * 3 * HDIM + tid];
    w0s[HDIM + tid]   = W0[m * 3 * HDIM + HDIM + tid];
    w0s[2*HDIM + tid] = W0[m * 3 * HDIM + 2 * HDIM + tid];
    b0s[tid] = b0[m * HDIM + tid];
    b1s[tid] = b1[m * HDIM + tid];
    b2s[tid] = b2[m * HDIM + tid];
    w3s[tid] = W3[m * HDIM + tid];
  }
  __syncthreads();
  const int off = s_base[0];
  const int cnt = s_base[1];
  const float mn0 = mins[3*m], mn1 = mins[3*m+1], mn2 = mins[3*m+2];
  const float mx0 = maxs[3*m], mx1 = maxs[3*m+1], mx2 = maxs[3*m+2];
  const float b3v = b3[m];
  const __bf16* Wt1m = Wt1 + m * HDIM * HDIM;
  const __bf16* Wt2m = Wt2 + m * HDIM * HDIM;

  const int lane = tid & 63;
  const int wave = tid >> 6;
  const int l16  = lane & 15;
  const int quad = lane >> 4;

  for (int tile = blockIdx.x; tile * TILE < cnt; tile += gridDim.x) {
    const int base = off + tile * TILE;
    const int npts = min(TILE, cnt - tile * TILE);

    if (tid < TILE) {
      if (tid < npts) {
        int p = perm[base + tid];
        pid[tid] = p;
        xs[tid][0] = -1.0f + 2.0f * (x[3*p]     - mn0) / (mx0 - mn0);
        xs[tid][1] = -1.0f + 2.0f * (x[3*p + 1] - mn1) / (mx1 - mn1);
        xs[tid][2] = -1.0f + 2.0f * (x[3*p + 2] - mn2) / (mx2 - mn2);
      } else {
        pid[tid] = -1;
        xs[tid][0] = 0.0f; xs[tid][1] = 0.0f; xs[tid][2] = 0.0f;
      }
    }
    __syncthreads();

    // layer 0: fp32 VALU, K=3 -> hA bf16
    {
      const int p = tid & 63;
      const int j0 = (tid >> 6) * 32;
      const float xv0 = xs[p][0], xv1 = xs[p][1], xv2 = xs[p][2];
      #pragma unroll
      for (int j = j0; j < j0 + 32; j += 4) {
        bf16x4 pk;
        #pragma unroll
        for (int u = 0; u < 4; ++u) {
          float v = b0s[j+u] + xv0 * w0s[j+u] + xv1 * w0s[HDIM + j+u] + xv2 * w0s[2*HDIM + j+u];
          pk[u] = (__bf16)fmaxf(v, 0.0f);
        }
        *(bf16x4*)(hA + p * LDSH + j) = pk;
      }
    }
    __syncthreads();

    gemm_relu(hA, hB, Wt1m, b1s, wave, l16, quad);   // layer 1
    __syncthreads();
    gemm_relu(hB, hA, Wt2m, b2s, wave, l16, quad);   // layer 2
    __syncthreads();

    // layer 3: dot(h2, w3) with 4 lanes/point
    {
      const int p = tid >> 2;
      const int part = tid & 3;
      float s = 0.0f;
      #pragma unroll
      for (int kk = 0; kk < 4; ++kk) {
        bf16x8 hv = *(const bf16x8*)(hA + p * LDSH + part * 32 + kk * 8);
        const float* wp = w3s + part * 32 + kk * 8;
        #pragma unroll
        for (int u = 0; u < 8; ++u) s += (float)hv[u] * wp[u];
      }
      s += __shfl_xor(s, 1);
      s += __shfl_xor(s, 2);
      if (part == 0 && p < npts) out[pid[p]] = s + b3v;
    }
    __syncthreads();
  }
}

extern "C" void kernel_launch(void* const* d_in, const int* in_sizes, int n_in,
                              void* d_out, int out_size, void* d_ws, size_t ws_size,
                              hipStream_t stream)
{
  const float* x    = (const float*)d_in[0];
  const float* W0   = (const float*)d_in[1];
  const float* b0   = (const float*)d_in[2];
  const float* W1   = (const float*)d_in[3];
  const float* b1   = (const float*)d_in[4];
  const float* W2   = (const float*)d_in[5];
  const float* b2   = (const float*)d_in[6];
  const float* W3   = (const float*)d_in[7];
  const float* b3   = (const float*)d_in[8];
  const float* mins = (const float*)d_in[9];
  const float* maxs = (const float*)d_in[10];
  float* out = (float*)d_out;
  const int N = in_sizes[0] / 3;

  char* ws = (char*)d_ws;
  int* counts  = (int*)ws;            // [0,32): counts
  int* cursors = counts + NMODEL;     // [32,64): cursors
  int* perm    = counts + 16;         // [64, 64+4N)
  __bf16* Wt1  = (__bf16*)(ws + 64 + (size_t)4 * N);
  __bf16* Wt2  = Wt1 + NMODEL * HDIM * HDIM;

  srn_prep<<<dim3(NMODEL * HDIM * HDIM / 256), dim3(256), 0, stream>>>(W1, W2, Wt1, Wt2, counts);
  srn_count<<<dim3((N + 255) / 256), dim3(256), 0, stream>>>(x, counts, N);
  srn_scan<<<dim3(1), dim3(64), 0, stream>>>(counts, cursors);
  srn_scatter<<<dim3((N + 255) / 256), dim3(256), 0, stream>>>(x, cursors, perm, N);
  srn_main<<<dim3(TILES_X, NMODEL), dim3(256), 0, stream>>>(
      x, W0, b0, b1, b2, W3, b3, mins, maxs, Wt1, Wt2, counts, perm, out);
}

// Round 2
// 111.197 us; speedup vs baseline: 1.1315x; 1.1315x over previous
//
#include <hip/hip_runtime.h>
#include <hip/hip_bf16.h>

// Ensemble SRN: 8 sub-models (2x2x2 octants), MLP 3->128->128->128->1, ReLU.
// R2: 3-node pipeline (memset cursors -> fused transpose+scatter -> MFMA main).
// perm uses fixed-capacity segments perm[m*N + slot]; cursors[m] == count[m].
// ws layout: [0,64)               cursors[8]
//            [64, 64+4*N*8)       perm segments (4 MB at N=131072)
//            [.., +256KB)         Wt1 bf16 [8][128][128]  (transposed: [n][k])
//            [.., +256KB)         Wt2 bf16 [8][128][128]

#define HDIM 128
#define LDSH 136      // padded LDS stride (bf16): 272B rows -> 2-way bank alias (free)
#define TILE 64
#define NMODEL 8
#define TILES_X 272

typedef __bf16 bf16x8 __attribute__((ext_vector_type(8)));
typedef __bf16 bf16x4 __attribute__((ext_vector_type(4)));
typedef float  f32x4  __attribute__((ext_vector_type(4)));

__device__ __forceinline__ int model_of(float x0, float x1, float x2) {
  // match reference: u=(x+1)/(2+1e-6); cell=int(u_flipped*2); idx=c0+2c1+4c2
  const float den = 2.000001f;
  float u0 = (x0 + 1.0f) / den;
  float u1 = (x1 + 1.0f) / den;
  float u2 = (x2 + 1.0f) / den;
  int c0 = (int)(u2 * 2.0f);
  int c1 = (int)(u1 * 2.0f);
  int c2 = (int)(u0 * 2.0f);
  return c0 + (c1 << 1) + (c2 << 2);
}

// ---------- fused: weight transpose (blocks 0..63) + point scatter (rest) ----------
__global__ __launch_bounds__(256)
void srn_prep_scatter(const float* __restrict__ W1, const float* __restrict__ W2,
                      const float* __restrict__ x,
                      __bf16* __restrict__ Wt1, __bf16* __restrict__ Wt2,
                      int* __restrict__ cursors, int* __restrict__ perm, int N)
{
  const int b = blockIdx.x;
  const int tid = threadIdx.x;

  if (b < 64) {
    // ---- transpose one 64x64 fp32 tile -> bf16 Wt[n][k] ----
    __shared__ float lds[64][65];   // +1 pad: column reads conflict-free
    const int m   = b >> 3;
    const int r2  = b & 7;
    const int mat = r2 >> 2;
    const int ti  = (r2 >> 1) & 1;  // k-tile
    const int tj  = r2 & 1;         // n-tile
    const float* src = (mat ? W2 : W1) + m * HDIM * HDIM;
    __bf16*      dst = (mat ? Wt2 : Wt1) + m * HDIM * HDIM;
    #pragma unroll
    for (int it = 0; it < 16; ++it) {
      const int rr = (tid >> 6) + it * 4, cc = tid & 63;
      lds[rr][cc] = src[(ti * 64 + rr) * HDIM + tj * 64 + cc];   // coalesced 256B rows
    }
    __syncthreads();
    #pragma unroll
    for (int it = 0; it < 16; ++it) {
      const int nn = (tid >> 6) + it * 4, kk = tid & 63;
      dst[(tj * 64 + nn) * HDIM + ti * 64 + kk] = (__bf16)lds[kk][nn];  // coalesced 128B rows
    }
  } else {
    // ---- scatter 1024 points/block into per-model segments ----
    __shared__ int lc[NMODEL], lb[NMODEL];
    if (tid < NMODEL) lc[tid] = 0;
    __syncthreads();
    const int base = (b - 64) * 1024;
    int ids[4], rs[4];
    #pragma unroll
    for (int it = 0; it < 4; ++it) {
      const int i = base + it * 256 + tid;
      if (i < N) {
        ids[it] = model_of(x[3*i], x[3*i+1], x[3*i+2]);
        rs[it] = atomicAdd(&lc[ids[it]], 1);
      } else ids[it] = -1;
    }
    __syncthreads();
    if (tid < NMODEL) lb[tid] = lc[tid] ? atomicAdd(&cursors[tid], lc[tid]) : 0;
    __syncthreads();
    #pragma unroll
    for (int it = 0; it < 4; ++it) {
      const int i = base + it * 256 + tid;
      if (i < N) perm[ids[it] * N + lb[ids[it]] + rs[it]] = i;
    }
  }
}

// ---------- GEMM layer: hOut = relu(hIn @ W + b), [64x128]x[128x128] bf16 MFMA ----------
// wave w owns col-tiles {2w, 2w+1} for all 4 row-tiles -> no intra-block B duplication.
__device__ __forceinline__ void gemm_relu(const __bf16* __restrict__ hIn,
                                          __bf16* __restrict__ hOut,
                                          const __bf16* __restrict__ Wt,
                                          const float* __restrict__ bias,
                                          int wave, int l16, int quad)
{
  const int n0 = wave * 32;
  f32x4 acc[4][2] = {};
  #pragma unroll
  for (int kk = 0; kk < 4; ++kk) {
    const int kOff = kk * 32 + quad * 8;
    bf16x8 bv0 = *(const bf16x8*)(Wt + (n0 + l16) * HDIM + kOff);
    bf16x8 bv1 = *(const bf16x8*)(Wt + (n0 + 16 + l16) * HDIM + kOff);
    #pragma unroll
    for (int r = 0; r < 4; ++r) {
      bf16x8 av = *(const bf16x8*)(hIn + (r * 16 + l16) * LDSH + kOff);
      acc[r][0] = __builtin_amdgcn_mfma_f32_16x16x32_bf16(av, bv0, acc[r][0], 0, 0, 0);
      acc[r][1] = __builtin_amdgcn_mfma_f32_16x16x32_bf16(av, bv1, acc[r][1], 0, 0, 0);
    }
  }
  const float bv0 = bias[n0 + l16];
  const float bv1 = bias[n0 + 16 + l16];
  #pragma unroll
  for (int r = 0; r < 4; ++r) {
    #pragma unroll
    for (int c = 0; c < 2; ++c) {
      const int n = n0 + c * 16 + l16;
      const float bb = c ? bv1 : bv0;
      #pragma unroll
      for (int i = 0; i < 4; ++i) {
        const int row = r * 16 + quad * 4 + i;   // C/D: col=lane&15, row=quad*4+reg
        float v = acc[r][c][i] + bb;
        hOut[row * LDSH + n] = (__bf16)fmaxf(v, 0.0f);
      }
    }
  }
}

// ---------- main: per-model tiled MLP ----------
__global__ __launch_bounds__(256, 4)
void srn_main(const float* __restrict__ x,
              const float* __restrict__ W0, const float* __restrict__ b0,
              const float* __restrict__ b1, const float* __restrict__ b2,
              const float* __restrict__ W3, const float* __restrict__ b3,
              const float* __restrict__ mins, const float* __restrict__ maxs,
              const __bf16* __restrict__ Wt1, const __bf16* __restrict__ Wt2,
              const int* __restrict__ cursors, const int* __restrict__ perm,
              float* __restrict__ out, int N)
{
  __shared__ __align__(16) __bf16 hA[TILE * LDSH];
  __shared__ __align__(16) __bf16 hB[TILE * LDSH];
  __shared__ float xs[TILE][3];
  __shared__ int   pid[TILE];
  __shared__ float w0s[3 * HDIM];
  __shared__ float b0s[HDIM], b1s[HDIM], b2s[HDIM], w3s[HDIM];

  const int m = blockIdx.y;
  const int tid = threadIdx.x;

  if (tid < HDIM) {
    w0s[tid]          = W0[m * 3 * HDIM + tid];
    w0s[HDIM + tid]   = W0[m * 3 * HDIM + HDIM + tid];
    w0s[2*HDIM + tid] = W0[m * 3 * HDIM + 2 * HDIM + tid];
    b0s[tid] = b0[m * HDIM + tid];
    b1s[tid] = b1[m * HDIM + tid];
    b2s[tid] = b2[m * HDIM + tid];
    w3s[tid] = W3[m * HDIM + tid];
  }
  const int cnt = cursors[m];
  const int* permSeg = perm + (size_t)m * N;
  const float mn0 = mins[3*m], mn1 = mins[3*m+1], mn2 = mins[3*m+2];
  const float mx0 = maxs[3*m], mx1 = maxs[3*m+1], mx2 = maxs[3*m+2];
  const float b3v = b3[m];
  const __bf16* Wt1m = Wt1 + m * HDIM * HDIM;
  const __bf16* Wt2m = Wt2 + m * HDIM * HDIM;
  __syncthreads();

  const int lane = tid & 63;
  const int wave = tid >> 6;
  const int l16  = lane & 15;
  const int quad = lane >> 4;

  for (int tile = blockIdx.x; tile * TILE < cnt; tile += gridDim.x) {
    const int base = tile * TILE;
    const int npts = min(TILE, cnt - base);

    if (tid < TILE) {
      if (tid < npts) {
        int p = permSeg[base + tid];
        pid[tid] = p;
        xs[tid][0] = -1.0f + 2.0f * (x[3*p]     - mn0) / (mx0 - mn0);
        xs[tid][1] = -1.0f + 2.0f * (x[3*p + 1] - mn1) / (mx1 - mn1);
        xs[tid][2] = -1.0f + 2.0f * (x[3*p + 2] - mn2) / (mx2 - mn2);
      } else {
        pid[tid] = -1;
        xs[tid][0] = 0.0f; xs[tid][1] = 0.0f; xs[tid][2] = 0.0f;
      }
    }
    __syncthreads();

    // layer 0: fp32 VALU, K=3 -> hA bf16
    {
      const int p = tid & 63;
      const int j0 = (tid >> 6) * 32;
      const float xv0 = xs[p][0], xv1 = xs[p][1], xv2 = xs[p][2];
      #pragma unroll
      for (int j = j0; j < j0 + 32; j += 4) {
        bf16x4 pk;
        #pragma unroll
        for (int u = 0; u < 4; ++u) {
          float v = b0s[j+u] + xv0 * w0s[j+u] + xv1 * w0s[HDIM + j+u] + xv2 * w0s[2*HDIM + j+u];
          pk[u] = (__bf16)fmaxf(v, 0.0f);
        }
        *(bf16x4*)(hA + p * LDSH + j) = pk;
      }
    }
    __syncthreads();

    gemm_relu(hA, hB, Wt1m, b1s, wave, l16, quad);   // layer 1
    __syncthreads();
    gemm_relu(hB, hA, Wt2m, b2s, wave, l16, quad);   // layer 2
    __syncthreads();

    // layer 3: dot(h2, w3) with 4 lanes/point
    {
      const int p = tid >> 2;
      const int part = tid & 3;
      float s = 0.0f;
      #pragma unroll
      for (int kk = 0; kk < 4; ++kk) {
        bf16x8 hv = *(const bf16x8*)(hA + p * LDSH + part * 32 + kk * 8);
        const float* wp = w3s + part * 32 + kk * 8;
        #pragma unroll
        for (int u = 0; u < 8; ++u) s += (float)hv[u] * wp[u];
      }
      s += __shfl_xor(s, 1);
      s += __shfl_xor(s, 2);
      if (part == 0 && p < npts) out[pid[p]] = s + b3v;
    }
    __syncthreads();
  }
}

extern "C" void kernel_launch(void* const* d_in, const int* in_sizes, int n_in,
                              void* d_out, int out_size, void* d_ws, size_t ws_size,
                              hipStream_t stream)
{
  const float* x    = (const float*)d_in[0];
  const float* W0   = (const float*)d_in[1];
  const float* b0   = (const float*)d_in[2];
  const float* W1   = (const float*)d_in[3];
  const float* b1   = (const float*)d_in[4];
  const float* W2   = (const float*)d_in[5];
  const float* b2   = (const float*)d_in[6];
  const float* W3   = (const float*)d_in[7];
  const float* b3   = (const float*)d_in[8];
  const float* mins = (const float*)d_in[9];
  const float* maxs = (const float*)d_in[10];
  float* out = (float*)d_out;
  const int N = in_sizes[0] / 3;

  char* ws = (char*)d_ws;
  int* cursors = (int*)ws;                                   // [0,32)
  int* perm    = (int*)(ws + 64);                            // 8 segments x N ints
  __bf16* Wt1  = (__bf16*)(ws + 64 + (size_t)4 * N * NMODEL);
  __bf16* Wt2  = Wt1 + NMODEL * HDIM * HDIM;

  hipMemsetAsync(cursors, 0, NMODEL * sizeof(int), stream);
  const int sb = (N + 1023) >> 10;
  srn_prep_scatter<<<dim3(64 + sb), dim3(256), 0, stream>>>(W1, W2, x, Wt1, Wt2, cursors, perm, N);
  srn_main<<<dim3(TILES_X, NMODEL), dim3(256), 0, stream>>>(
      x, W0, b0, b1, b2, W3, b3, mins, maxs, Wt1, Wt2, cursors, perm, out, N);
}